// Round 1
// 218.111 us; speedup vs baseline: 1.0104x; 1.0104x over previous
//
#include <hip/hip_runtime.h>
#include <hip/hip_bf16.h>

#define EMBED 256
#define NH 8
#define NL 4
#define NP 4
#define HD 32
#define BS 4
#define NQ 4000
#define NV 13294

using f32x4   = __attribute__((ext_vector_type(4))) float;
using bf16x8  = __attribute__((ext_vector_type(8))) short;

__device__ __forceinline__ float bf2f_lo(unsigned u) {
    union { unsigned u; float f; } x; x.u = u << 16; return x.f;
}
__device__ __forceinline__ float bf2f_hi(unsigned u) {
    union { unsigned u; float f; } x; x.u = u & 0xffff0000u; return x.f;
}
__device__ __forceinline__ unsigned short f2bf(float f) {
    union { float f; unsigned u; } x; x.f = f;
    unsigned u = x.u;
    return (unsigned short)((u + 0x7fffu + ((u >> 16) & 1u)) >> 16);
}

// async 16B/lane global->LDS DMA (global_load_lds_dwordx4).
// LDS dest is wave-uniform base; lane i lands at base + i*16.
__device__ __forceinline__ void async16(const void* g, void* l) {
    __builtin_amdgcn_global_load_lds(
        (const __attribute__((address_space(1))) void*)g,
        (__attribute__((address_space(3))) void*)l, 16, 0, 0);
}

// ---------- prep: weight transposes + bias concat only (value/query cvt fused into GEMMs) ----------
__global__ __launch_bounds__(256) void msda_prep_k(
    const float* __restrict__ W_val, const float* __restrict__ W_out,
    const float* __restrict__ W_off, const float* __restrict__ W_attn,
    const float* __restrict__ b_off, const float* __restrict__ b_attn,
    unsigned short* __restrict__ Wt_val, unsigned short* __restrict__ Wt_out,
    unsigned short* __restrict__ Wt_qa, float* __restrict__ b_qa)
{
    int i = blockIdx.x * 256 + threadIdx.x;      // 896 blocks -> 229,376 elems
    if (i < 384) b_qa[i] = (i < 256) ? b_off[i] : b_attn[i - 256];
    if (i < 65536) {
        int r = i >> 8, c = i & 255;
        Wt_val[c * 256 + r] = f2bf(W_val[i]);
    } else if (i < 131072) {
        int j = i - 65536, r = j >> 8, c = j & 255;
        Wt_out[c * 256 + r] = f2bf(W_out[j]);
    } else if (i < 229376) {
        int j = i - 131072;              // j = n*256 + k, n in [0,384)
        int n = j >> 8, k = j & 255;
        float v = (n < 256) ? W_off[k * 256 + n] : W_attn[k * 128 + (n - 256)];
        Wt_qa[j] = f2bf(v);
    }
}

// ---------- GEMM: TM x 128 tile, double-buffered prefetch ----------
// AF32=false: A bf16 [M][K], staged via global_load_lds DMA.
// AF32=true:  A fp32 [M][K], reg-staged (float4 load -> f2bf -> ds_write_b64) --
//             fuses the fp32->bf16 conversion, eliminating the prep copy pass.
// Bt = B^T bf16 [N][K] (DMA path), bias fp32 [N].
// EPI 0: bf16 row-major [M][N];  EPI 1: fp32 row-major [M][N].
template<int TM, int EPI, bool AF32>
__global__ __launch_bounds__(256) void msda_gemm_k(
    const void* __restrict__ Ap,
    const unsigned short* __restrict__ Bt,
    const float* __restrict__ bias,
    void* __restrict__ out,
    int M, int N, int K)
{
    constexpr int NI = (TM == 128) ? 4 : 2;
    constexpr int AREPS = TM / 32;               // float4 reps/thread/chunk (AF32 path)
    __shared__ __align__(16) unsigned short As[2][TM][32];
    __shared__ __align__(16) unsigned short Bs[2][128][32];
    const int m0 = blockIdx.x * TM, n0 = blockIdx.y * 128;
    const int tid  = threadIdx.x;
    const int w    = tid >> 6;
    const int lane = tid & 63;
    const int quad = lane >> 4;
    const int l16  = lane & 15;
    const int wm   = (TM == 128) ? (w & 1) * 64 : 0;
    const int wn   = (TM == 128) ? (w >> 1) * 64 : w * 32;

    // DMA staging geometry: segment = 16 rows x 64 B; lane -> (row lane>>2, 16B chunk lane&3)
    const int rseg = lane >> 2;
    const int cb   = (lane & 3) * 16;

    const char* bgp0 = (const char*)(Bt + (size_t)(n0 + (2 * w) * 16 + rseg) * K) + cb;
    const char* bgp1 = (const char*)(Bt + (size_t)(n0 + (2 * w + 1) * 16 + rseg) * K) + cb;

    // ---- A staging state ----
    const char* agp0 = nullptr; const char* agp1 = nullptr;      // bf16 DMA path
    const float* afp[AREPS];                                     // fp32 reg-staged path
    const int lr = tid >> 3;          // row within 32-row group
    const int lk = (tid & 7) * 4;     // col (floats / bf16 elems)
    if constexpr (AF32) {
        const float* Af = (const float*)Ap;
#pragma unroll
        for (int j = 0; j < AREPS; j++) {
            int rowg = min(m0 + j * 32 + lr, M - 1);
            afp[j] = Af + (size_t)rowg * K + lk;
        }
    } else {
        const unsigned short* Abf = (const unsigned short*)Ap;
        int ar0, ar1 = 0;
        if (TM == 128) {
            ar0 = min(m0 + (2 * w) * 16 + rseg, M - 1);
            ar1 = min(m0 + (2 * w + 1) * 16 + rseg, M - 1);
        } else {
            ar0 = min(m0 + w * 16 + rseg, M - 1);
        }
        agp0 = (const char*)(Abf + (size_t)ar0 * K) + cb;
        agp1 = (TM == 128) ? (const char*)(Abf + (size_t)ar1 * K) + cb : agp0;
    }

    auto issueB = [&](int chunk, int buf) {
        const int kb = chunk * 64;   // chunk * 32 elems * 2 B
        char* b = (char*)&Bs[buf][0][0];
        async16(bgp0 + kb, b + (2 * w) * 1024);
        async16(bgp1 + kb, b + (2 * w + 1) * 1024);
    };
    auto issueAbf = [&](int chunk, int buf) {
        const int kb = chunk * 64;
        char* a = (char*)&As[buf][0][0];
        if (TM == 128) {
            async16(agp0 + kb, a + (2 * w) * 1024);
            async16(agp1 + kb, a + (2 * w + 1) * 1024);
        } else {
            async16(agp0 + kb, a + w * 1024);
        }
    };

    float4 areg[AREPS];
    auto loadA = [&](int chunk) {
#pragma unroll
        for (int j = 0; j < AREPS; j++)
            areg[j] = *(const float4*)(afp[j] + chunk * 32);
    };
    auto writeA = [&](int buf) {
#pragma unroll
        for (int j = 0; j < AREPS; j++) {
            uint2 o = { (unsigned)f2bf(areg[j].x) | ((unsigned)f2bf(areg[j].y) << 16),
                        (unsigned)f2bf(areg[j].z) | ((unsigned)f2bf(areg[j].w) << 16) };
            *(uint2*)&As[buf][j * 32 + lr][lk] = o;
        }
    };

    f32x4 acc[4][NI];
#pragma unroll
    for (int a = 0; a < 4; a++)
#pragma unroll
        for (int b = 0; b < NI; b++) acc[a][b] = (f32x4){0.f, 0.f, 0.f, 0.f};

    const int C = K / 32;
    if constexpr (AF32) {
        loadA(0); issueB(0, 0); writeA(0);       // writeA waits vmcnt internally
    } else {
        issueAbf(0, 0); issueB(0, 0);
    }
    for (int c = 0; c < C; c++) {
        __syncthreads();                 // drains chunk c DMA (vmcnt) + makes A ds_writes visible
        const int buf = c & 1;
        const bool pf = (c + 1 < C);
        if (pf) {
            if constexpr (AF32) loadA(c + 1);    // global fp32 loads in flight across compute(c)
            else issueAbf(c + 1, (c + 1) & 1);
            issueB(c + 1, (c + 1) & 1);
        }
        bf16x8 af[4], bfr[NI];
#pragma unroll
        for (int mi = 0; mi < 4; mi++)  af[mi]  = *(const bf16x8*)&As[buf][wm + mi * 16 + l16][quad * 8];
#pragma unroll
        for (int ni = 0; ni < NI; ni++) bfr[ni] = *(const bf16x8*)&Bs[buf][wn + ni * 16 + l16][quad * 8];
#pragma unroll
        for (int mi = 0; mi < 4; mi++)
#pragma unroll
            for (int ni = 0; ni < NI; ni++)
                acc[mi][ni] = __builtin_amdgcn_mfma_f32_16x16x32_bf16(af[mi], bfr[ni], acc[mi][ni], 0, 0, 0);
        if constexpr (AF32) {
            // buf (c+1)&1 was last read in iter c-1; all waves passed this iter's barrier,
            // so writing it now is race-free.
            if (pf) writeA((c + 1) & 1);
        }
    }

#pragma unroll
    for (int ni = 0; ni < NI; ni++) {
        int cc = n0 + wn + ni * 16 + l16;
        float bvv = bias[cc];
#pragma unroll
        for (int mi = 0; mi < 4; mi++) {
#pragma unroll
            for (int r = 0; r < 4; r++) {
                int m = m0 + wm + mi * 16 + quad * 4 + r;
                if (m >= M) continue;
                float val = acc[mi][ni][r] + bvv;
                if (EPI == 0) {
                    ((unsigned short*)out)[(size_t)m * N + cc] = f2bf(val);
                } else {
                    ((float*)out)[(size_t)m * N + cc] = val;
                }
            }
        }
    }
}

// ---------- sampler: 4 queries/block, wave = 1 query, thread = (h, 4-chan grp) ----------
__global__ __launch_bounds__(256) void msda_sampler_k(
    const float* __restrict__ refpts,            // (BS*NQ, 8) fp32
    const float* __restrict__ oa_buf,            // (BS*NQ, 384) fp32: off[256] | attn[128]
    const unsigned short* __restrict__ v_buf,    // (BS*NV, 256) bf16 row-major
    unsigned short* __restrict__ t_out)          // (BS*NQ, 256) bf16
{
    __shared__ float  oa_s[4][384];
    __shared__ float  ref_s[4][8];
    __shared__ float4 wtab[528];                 // idx = i*33 + ql*8 + h (stride-33 pad)
    __shared__ int4   itab[528];

    const int tid = threadIdx.x;
    const int q0  = blockIdx.x * 4;

    // phase 1: cooperative loads
    {
        const float4* src = (const float4*)(oa_buf + (size_t)q0 * 384);
        float4* dst = (float4*)&oa_s[0][0];
        dst[tid] = src[tid];
        if (tid < 128) dst[256 + tid] = src[256 + tid];
        if (tid < 32) ((float*)ref_s)[tid] = refpts[q0 * 8 + tid];
    }
    __syncthreads();

    // phase 2+3 fused: shuffle softmax (16 lanes = one (q,h) group) + tables
    const int HWs[4]    = {100, 50, 25, 13};
    const int starts[4] = {0, 10000, 12500, 13125};
#pragma unroll
    for (int it = 0; it < 2; it++) {
        int s  = tid + it * 256;                 // 0..511
        int i  = s & 15;                         // l*4+p
        int h  = (s >> 4) & 7;
        int ql = s >> 7;
        int l  = i >> 2, p = i & 3;
        float logit = oa_s[ql][256 + h * 16 + i];
        float m = logit;
#pragma unroll
        for (int off = 1; off < 16; off <<= 1) m = fmaxf(m, __shfl_xor(m, off, 64));
        float e = __expf(logit - m);
        float sum = e;
#pragma unroll
        for (int off = 1; off < 16; off <<= 1) sum += __shfl_xor(sum, off, 64);
        float a = e / sum;

        int Wl = HWs[l];
        float fW = (float)Wl;
        float rx = ref_s[ql][l * 2], ry = ref_s[ql][l * 2 + 1];
        float offx = oa_s[ql][h * 32 + l * 8 + p * 2];
        float offy = oa_s[ql][h * 32 + l * 8 + p * 2 + 1];
        float x = rx * fW + offx - 0.5f;
        float y = ry * fW + offy - 0.5f;
        float xf = floorf(x), yf = floorf(y);
        float fx = x - xf, fy = y - yf;
        int x0 = (int)xf, y0 = (int)yf;
        int x1 = x0 + 1, y1 = y0 + 1;
        float wx0 = (x0 >= 0 && x0 < Wl) ? (1.f - fx) : 0.f;
        float wx1 = (x1 >= 0 && x1 < Wl) ? fx : 0.f;
        float wy0 = (y0 >= 0 && y0 < Wl) ? (1.f - fy) : 0.f;
        float wy1 = (y1 >= 0 && y1 < Wl) ? fy : 0.f;
        int x0c = min(max(x0, 0), Wl - 1), x1c = min(max(x1, 0), Wl - 1);
        int y0c = min(max(y0, 0), Wl - 1), y1c = min(max(y1, 0), Wl - 1);
        int r0 = starts[l] + y0c * Wl, r1 = starts[l] + y1c * Wl;
        int ti = i * 33 + ql * 8 + h;
        wtab[ti] = make_float4(wx0 * wy0 * a, wx1 * wy0 * a, wx0 * wy1 * a, wx1 * wy1 * a);
        itab[ti] = make_int4(r0 + x0c, r0 + x1c, r1 + x0c, r1 + x1c);
    }
    __syncthreads();

    // phase 4: gather + weighted accumulate, 4 channels per thread
    const int dg = tid & 7, h = (tid >> 3) & 7, ql = tid >> 6;
    const int q = q0 + ql;
    const int b = q / NQ;
    const char* base = (const char*)v_buf + (size_t)b * NV * 512;
    const unsigned hd8 = (unsigned)h * 64 + (unsigned)dg * 8;
    const int tbase = ql * 8 + h;

    float a0 = 0.f, a1 = 0.f, a2 = 0.f, a3 = 0.f;
#pragma unroll
    for (int lp = 0; lp < 16; lp++) {
        float4 wv = wtab[lp * 33 + tbase];
        int4   ix = itab[lp * 33 + tbase];
        uint2 s0 = *(const uint2*)(base + (((unsigned)ix.x << 9) + hd8));
        uint2 s1 = *(const uint2*)(base + (((unsigned)ix.y << 9) + hd8));
        uint2 s2 = *(const uint2*)(base + (((unsigned)ix.z << 9) + hd8));
        uint2 s3 = *(const uint2*)(base + (((unsigned)ix.w << 9) + hd8));
        a0 += wv.x * bf2f_lo(s0.x); a1 += wv.x * bf2f_hi(s0.x);
        a2 += wv.x * bf2f_lo(s0.y); a3 += wv.x * bf2f_hi(s0.y);
        a0 += wv.y * bf2f_lo(s1.x); a1 += wv.y * bf2f_hi(s1.x);
        a2 += wv.y * bf2f_lo(s1.y); a3 += wv.y * bf2f_hi(s1.y);
        a0 += wv.z * bf2f_lo(s2.x); a1 += wv.z * bf2f_hi(s2.x);
        a2 += wv.z * bf2f_lo(s2.y); a3 += wv.z * bf2f_hi(s2.y);
        a0 += wv.w * bf2f_lo(s3.x); a1 += wv.w * bf2f_hi(s3.x);
        a2 += wv.w * bf2f_lo(s3.y); a3 += wv.w * bf2f_hi(s3.y);
    }
    unsigned o0 = (unsigned)f2bf(a0) | ((unsigned)f2bf(a1) << 16);
    unsigned o1 = (unsigned)f2bf(a2) | ((unsigned)f2bf(a3) << 16);
    uint2 o = {o0, o1};
    *(uint2*)(t_out + (size_t)q * 256 + h * 32 + dg * 4) = o;
}

extern "C" void kernel_launch(void* const* d_in, const int* in_sizes, int n_in,
                              void* d_out, int out_size, void* d_ws, size_t ws_size,
                              hipStream_t stream) {
    const float* query  = (const float*)d_in[0];
    const float* value  = (const float*)d_in[1];
    const float* refpts = (const float*)d_in[2];
    // d_in[3] = spatial_shapes (int32) — fixed {100,50,25,13}^2, hard-coded.
    const float* W_off  = (const float*)d_in[4];
    const float* b_off  = (const float*)d_in[5];
    const float* W_attn = (const float*)d_in[6];
    const float* b_attn = (const float*)d_in[7];
    const float* W_val  = (const float*)d_in[8];
    const float* b_val  = (const float*)d_in[9];
    const float* W_out  = (const float*)d_in[10];
    const float* b_out  = (const float*)d_in[11];

    char* wsp = (char*)d_ws;
    size_t o = 0;
    auto carve = [&](size_t bytes) -> void* {
        void* p = wsp + o; o += (bytes + 255) & ~(size_t)255; return p;
    };
    unsigned short* Wt_val = (unsigned short*)carve(256 * 256 * 2);
    unsigned short* Wt_out = (unsigned short*)carve(256 * 256 * 2);
    unsigned short* Wt_qa  = (unsigned short*)carve(384 * 256 * 2);
    float*          b_qa   = (float*)carve(384 * 4);
    unsigned short* v_buf  = (unsigned short*)carve((size_t)BS * NV * EMBED * 2);
    float*          oa_buf = (float*)carve((size_t)BS * NQ * 384 * 4);
    unsigned short* t_buf  = (unsigned short*)carve((size_t)BS * NQ * EMBED * 2);

    msda_prep_k<<<896, 256, 0, stream>>>(W_val, W_out, W_off, W_attn,
                                         b_off, b_attn, Wt_val, Wt_out, Wt_qa, b_qa);

    const int Mv = BS * NV;   // 53176
    const int Mq = BS * NQ;   // 16000
    // value GEMM reads fp32 value directly (conversion fused into A-staging)
    msda_gemm_k<128, 0, true><<<dim3((Mv + 127) / 128, 2), 256, 0, stream>>>(value, Wt_val, b_val, v_buf, Mv, 256, 256);
    // qa GEMM reads fp32 query directly
    msda_gemm_k<64, 1, true><<<dim3(Mq / 64, 3), 256, 0, stream>>>(query, Wt_qa, b_qa, oa_buf, Mq, 384, 256);
    // sampler reads oa_buf, writes t_buf
    msda_sampler_k<<<Mq / 4, 256, 0, stream>>>(refpts, oa_buf, v_buf, t_buf);
    // out GEMM reads bf16 t_buf via DMA path
    msda_gemm_k<64, 1, false><<<dim3(Mq / 64, 2), 256, 0, stream>>>(t_buf, Wt_out, b_out, (float*)d_out, Mq, 256, 256);
}

// Round 2
// 206.193 us; speedup vs baseline: 1.0688x; 1.0578x over previous
//
#include <hip/hip_runtime.h>
#include <hip/hip_bf16.h>

#define EMBED 256
#define NH 8
#define NL 4
#define NP 4
#define HD 32
#define BS 4
#define NQ 4000
#define NV 13294

using f32x4   = __attribute__((ext_vector_type(4))) float;
using bf16x8  = __attribute__((ext_vector_type(8))) short;

__device__ __forceinline__ float bf2f_lo(unsigned u) {
    union { unsigned u; float f; } x; x.u = u << 16; return x.f;
}
__device__ __forceinline__ float bf2f_hi(unsigned u) {
    union { unsigned u; float f; } x; x.u = u & 0xffff0000u; return x.f;
}
__device__ __forceinline__ unsigned short f2bf(float f) {
    union { float f; unsigned u; } x; x.f = f;
    unsigned u = x.u;
    return (unsigned short)((u + 0x7fffu + ((u >> 16) & 1u)) >> 16);
}

// async 16B/lane global->LDS DMA (global_load_lds_dwordx4).
// LDS dest is wave-uniform base; lane i lands at base + i*16.
__device__ __forceinline__ void async16(const void* g, void* l) {
    __builtin_amdgcn_global_load_lds(
        (const __attribute__((address_space(1))) void*)g,
        (__attribute__((address_space(3))) void*)l, 16, 0, 0);
}

// ---------- prep: weight transposes + bias concat only ----------
__global__ __launch_bounds__(256) void msda_prep_k(
    const float* __restrict__ W_val, const float* __restrict__ W_out,
    const float* __restrict__ W_off, const float* __restrict__ W_attn,
    const float* __restrict__ b_off, const float* __restrict__ b_attn,
    unsigned short* __restrict__ Wt_val, unsigned short* __restrict__ Wt_out,
    unsigned short* __restrict__ Wt_qa, float* __restrict__ b_qa)
{
    int i = blockIdx.x * 256 + threadIdx.x;      // 896 blocks -> 229,376 elems
    if (i < 384) b_qa[i] = (i < 256) ? b_off[i] : b_attn[i - 256];
    if (i < 65536) {
        int r = i >> 8, c = i & 255;
        Wt_val[c * 256 + r] = f2bf(W_val[i]);
    } else if (i < 131072) {
        int j = i - 65536, r = j >> 8, c = j & 255;
        Wt_out[c * 256 + r] = f2bf(W_out[j]);
    } else if (i < 229376) {
        int j = i - 131072;              // j = n*256 + k, n in [0,384)
        int n = j >> 8, k = j & 255;
        float v = (n < 256) ? W_off[k * 256 + n] : W_attn[k * 128 + (n - 256)];
        Wt_qa[j] = f2bf(v);
    }
}

// ---------- GEMM body: TM x 128 tile, double-buffered prefetch ----------
// AF32=false: A bf16 [M][K], staged via global_load_lds DMA.
// AF32=true:  A fp32 [M][K], reg-staged (float4 load -> f2bf -> ds_write_b64).
// Bt = B^T bf16 [N][K] (DMA path), bias fp32 [N].
// EPI 0: bf16 row-major [M][N];  EPI 1: fp32 row-major [M][N].
// LDS layout (dynamic): As[2][TM][32] then Bs[2][128][32].
template<int TM, int EPI, bool AF32>
__device__ __forceinline__ void gemm_body(
    char* lds,
    const void* __restrict__ Ap,
    const unsigned short* __restrict__ Bt,
    const float* __restrict__ bias,
    void* __restrict__ out,
    int M, int N, int K, int mblk, int nblk)
{
    constexpr int NI = (TM == 128) ? 4 : 2;
    constexpr int AREPS = TM / 32;               // float4 reps/thread/chunk (AF32 path)
    typedef unsigned short AsArr[TM][32];
    typedef unsigned short BsArr[128][32];
    AsArr* As = (AsArr*)lds;                          // As[2][TM][32]
    BsArr* Bs = (BsArr*)(lds + 2 * TM * 32 * 2);      // Bs[2][128][32]

    const int m0 = mblk * TM, n0 = nblk * 128;
    const int tid  = threadIdx.x;
    const int w    = tid >> 6;
    const int lane = tid & 63;
    const int quad = lane >> 4;
    const int l16  = lane & 15;
    const int wm   = (TM == 128) ? (w & 1) * 64 : 0;
    const int wn   = (TM == 128) ? (w >> 1) * 64 : w * 32;

    // DMA staging geometry: segment = 16 rows x 64 B; lane -> (row lane>>2, 16B chunk lane&3)
    const int rseg = lane >> 2;
    const int cb   = (lane & 3) * 16;

    const char* bgp0 = (const char*)(Bt + (size_t)(n0 + (2 * w) * 16 + rseg) * K) + cb;
    const char* bgp1 = (const char*)(Bt + (size_t)(n0 + (2 * w + 1) * 16 + rseg) * K) + cb;

    // ---- A staging state ----
    const char* agp0 = nullptr; const char* agp1 = nullptr;      // bf16 DMA path
    const float* afp[AREPS];                                     // fp32 reg-staged path
    const int lr = tid >> 3;          // row within 32-row group
    const int lk = (tid & 7) * 4;     // col (floats / bf16 elems)
    if constexpr (AF32) {
        const float* Af = (const float*)Ap;
#pragma unroll
        for (int j = 0; j < AREPS; j++) {
            int rowg = min(m0 + j * 32 + lr, M - 1);
            afp[j] = Af + (size_t)rowg * K + lk;
        }
    } else {
        const unsigned short* Abf = (const unsigned short*)Ap;
        int ar0, ar1 = 0;
        if (TM == 128) {
            ar0 = min(m0 + (2 * w) * 16 + rseg, M - 1);
            ar1 = min(m0 + (2 * w + 1) * 16 + rseg, M - 1);
        } else {
            ar0 = min(m0 + w * 16 + rseg, M - 1);
        }
        agp0 = (const char*)(Abf + (size_t)ar0 * K) + cb;
        agp1 = (TM == 128) ? (const char*)(Abf + (size_t)ar1 * K) + cb : agp0;
    }

    auto issueB = [&](int chunk, int buf) {
        const int kb = chunk * 64;   // chunk * 32 elems * 2 B
        char* b = (char*)&Bs[buf][0][0];
        async16(bgp0 + kb, b + (2 * w) * 1024);
        async16(bgp1 + kb, b + (2 * w + 1) * 1024);
    };
    auto issueAbf = [&](int chunk, int buf) {
        const int kb = chunk * 64;
        char* a = (char*)&As[buf][0][0];
        if (TM == 128) {
            async16(agp0 + kb, a + (2 * w) * 1024);
            async16(agp1 + kb, a + (2 * w + 1) * 1024);
        } else {
            async16(agp0 + kb, a + w * 1024);
        }
    };

    float4 areg[AREPS];
    auto loadA = [&](int chunk) {
#pragma unroll
        for (int j = 0; j < AREPS; j++)
            areg[j] = *(const float4*)(afp[j] + chunk * 32);
    };
    auto writeA = [&](int buf) {
#pragma unroll
        for (int j = 0; j < AREPS; j++) {
            uint2 o = { (unsigned)f2bf(areg[j].x) | ((unsigned)f2bf(areg[j].y) << 16),
                        (unsigned)f2bf(areg[j].z) | ((unsigned)f2bf(areg[j].w) << 16) };
            *(uint2*)&As[buf][j * 32 + lr][lk] = o;
        }
    };

    f32x4 acc[4][NI];
#pragma unroll
    for (int a = 0; a < 4; a++)
#pragma unroll
        for (int b = 0; b < NI; b++) acc[a][b] = (f32x4){0.f, 0.f, 0.f, 0.f};

    const int C = K / 32;
    if constexpr (AF32) {
        loadA(0); issueB(0, 0); writeA(0);       // writeA waits vmcnt internally
    } else {
        issueAbf(0, 0); issueB(0, 0);
    }
    for (int c = 0; c < C; c++) {
        __syncthreads();                 // drains chunk c DMA (vmcnt) + makes A ds_writes visible
        const int buf = c & 1;
        const bool pf = (c + 1 < C);
        if (pf) {
            if constexpr (AF32) loadA(c + 1);    // global fp32 loads in flight across compute(c)
            else issueAbf(c + 1, (c + 1) & 1);
            issueB(c + 1, (c + 1) & 1);
        }
        bf16x8 af[4], bfr[NI];
#pragma unroll
        for (int mi = 0; mi < 4; mi++)  af[mi]  = *(const bf16x8*)&As[buf][wm + mi * 16 + l16][quad * 8];
#pragma unroll
        for (int ni = 0; ni < NI; ni++) bfr[ni] = *(const bf16x8*)&Bs[buf][wn + ni * 16 + l16][quad * 8];
#pragma unroll
        for (int mi = 0; mi < 4; mi++)
#pragma unroll
            for (int ni = 0; ni < NI; ni++)
                acc[mi][ni] = __builtin_amdgcn_mfma_f32_16x16x32_bf16(af[mi], bfr[ni], acc[mi][ni], 0, 0, 0);
        if constexpr (AF32) {
            // buf (c+1)&1 was last read in iter c-1; all waves passed this iter's barrier,
            // so writing it now is race-free.
            if (pf) writeA((c + 1) & 1);
        }
    }

#pragma unroll
    for (int ni = 0; ni < NI; ni++) {
        int cc = n0 + wn + ni * 16 + l16;
        float bvv = bias[cc];
#pragma unroll
        for (int mi = 0; mi < 4; mi++) {
#pragma unroll
            for (int r = 0; r < 4; r++) {
                int m = m0 + wm + mi * 16 + quad * 4 + r;
                if (m >= M) continue;
                float val = acc[mi][ni][r] + bvv;
                if (EPI == 0) {
                    ((unsigned short*)out)[(size_t)m * N + cc] = f2bf(val);
                } else {
                    ((float*)out)[(size_t)m * N + cc] = val;
                }
            }
        }
    }
}

// ---------- merged value-GEMM + qa-GEMM: one dispatch, block-range split ----------
// value: 832 blocks (416 m-tiles x 2 n-tiles, TM=128), qa: 750 blocks (250 x 3, TM=64).
// The two workloads are independent; co-residency overlaps their latency stalls.
__global__ __launch_bounds__(256, 4) void msda_gemm_vq_k(
    const float* __restrict__ value, const float* __restrict__ query,
    const unsigned short* __restrict__ Wt_val, const unsigned short* __restrict__ Wt_qa,
    const float* __restrict__ b_val, const float* __restrict__ b_qa,
    unsigned short* __restrict__ v_buf, float* __restrict__ oa_buf)
{
    extern __shared__ char lds[];
    const int bx = blockIdx.x;
    if (bx < 832) {
        gemm_body<128, 0, true>(lds, value, Wt_val, b_val, v_buf,
                                BS * NV, 256, 256, bx >> 1, bx & 1);
    } else {
        const int j = bx - 832;
        const int mb = j / 3;
        gemm_body<64, 1, true>(lds, query, Wt_qa, b_qa, oa_buf,
                               BS * NQ, 384, 256, mb, j - mb * 3);
    }
}

// ---------- out GEMM (after sampler) ----------
__global__ __launch_bounds__(256, 4) void msda_gemm_out_k(
    const unsigned short* __restrict__ t_buf,
    const unsigned short* __restrict__ Wt_out,
    const float* __restrict__ b_out,
    float* __restrict__ out)
{
    extern __shared__ char lds[];
    const int bx = blockIdx.x;
    gemm_body<64, 1, false>(lds, t_buf, Wt_out, b_out, out,
                            BS * NQ, 256, 256, bx >> 1, bx & 1);
}

// ---------- sampler: 4 queries/block, wave = 1 query, thread = (h, 4-chan grp) ----------
__global__ __launch_bounds__(256) void msda_sampler_k(
    const float* __restrict__ refpts,            // (BS*NQ, 8) fp32
    const float* __restrict__ oa_buf,            // (BS*NQ, 384) fp32: off[256] | attn[128]
    const unsigned short* __restrict__ v_buf,    // (BS*NV, 256) bf16 row-major
    unsigned short* __restrict__ t_out)          // (BS*NQ, 256) bf16
{
    __shared__ float  oa_s[4][384];
    __shared__ float  ref_s[4][8];
    __shared__ float4 wtab[528];                 // idx = i*33 + ql*8 + h (stride-33 pad)
    __shared__ int4   itab[528];

    const int tid = threadIdx.x;
    const int q0  = blockIdx.x * 4;

    // phase 1: cooperative loads
    {
        const float4* src = (const float4*)(oa_buf + (size_t)q0 * 384);
        float4* dst = (float4*)&oa_s[0][0];
        dst[tid] = src[tid];
        if (tid < 128) dst[256 + tid] = src[256 + tid];
        if (tid < 32) ((float*)ref_s)[tid] = refpts[q0 * 8 + tid];
    }
    __syncthreads();

    // phase 2+3 fused: shuffle softmax (16 lanes = one (q,h) group) + tables
    const int HWs[4]    = {100, 50, 25, 13};
    const int starts[4] = {0, 10000, 12500, 13125};
#pragma unroll
    for (int it = 0; it < 2; it++) {
        int s  = tid + it * 256;                 // 0..511
        int i  = s & 15;                         // l*4+p
        int h  = (s >> 4) & 7;
        int ql = s >> 7;
        int l  = i >> 2, p = i & 3;
        float logit = oa_s[ql][256 + h * 16 + i];
        float m = logit;
#pragma unroll
        for (int off = 1; off < 16; off <<= 1) m = fmaxf(m, __shfl_xor(m, off, 64));
        float e = __expf(logit - m);
        float sum = e;
#pragma unroll
        for (int off = 1; off < 16; off <<= 1) sum += __shfl_xor(sum, off, 64);
        float a = e / sum;

        int Wl = HWs[l];
        float fW = (float)Wl;
        float rx = ref_s[ql][l * 2], ry = ref_s[ql][l * 2 + 1];
        float offx = oa_s[ql][h * 32 + l * 8 + p * 2];
        float offy = oa_s[ql][h * 32 + l * 8 + p * 2 + 1];
        float x = rx * fW + offx - 0.5f;
        float y = ry * fW + offy - 0.5f;
        float xf = floorf(x), yf = floorf(y);
        float fx = x - xf, fy = y - yf;
        int x0 = (int)xf, y0 = (int)yf;
        int x1 = x0 + 1, y1 = y0 + 1;
        float wx0 = (x0 >= 0 && x0 < Wl) ? (1.f - fx) : 0.f;
        float wx1 = (x1 >= 0 && x1 < Wl) ? fx : 0.f;
        float wy0 = (y0 >= 0 && y0 < Wl) ? (1.f - fy) : 0.f;
        float wy1 = (y1 >= 0 && y1 < Wl) ? fy : 0.f;
        int x0c = min(max(x0, 0), Wl - 1), x1c = min(max(x1, 0), Wl - 1);
        int y0c = min(max(y0, 0), Wl - 1), y1c = min(max(y1, 0), Wl - 1);
        int r0 = starts[l] + y0c * Wl, r1 = starts[l] + y1c * Wl;
        int ti = i * 33 + ql * 8 + h;
        wtab[ti] = make_float4(wx0 * wy0 * a, wx1 * wy0 * a, wx0 * wy1 * a, wx1 * wy1 * a);
        itab[ti] = make_int4(r0 + x0c, r0 + x1c, r1 + x0c, r1 + x1c);
    }
    __syncthreads();

    // phase 4: gather + weighted accumulate, 4 channels per thread
    const int dg = tid & 7, h = (tid >> 3) & 7, ql = tid >> 6;
    const int q = q0 + ql;
    const int b = q / NQ;
    const char* base = (const char*)v_buf + (size_t)b * NV * 512;
    const unsigned hd8 = (unsigned)h * 64 + (unsigned)dg * 8;
    const int tbase = ql * 8 + h;

    float a0 = 0.f, a1 = 0.f, a2 = 0.f, a3 = 0.f;
#pragma unroll
    for (int lp = 0; lp < 16; lp++) {
        float4 wv = wtab[lp * 33 + tbase];
        int4   ix = itab[lp * 33 + tbase];
        uint2 s0 = *(const uint2*)(base + (((unsigned)ix.x << 9) + hd8));
        uint2 s1 = *(const uint2*)(base + (((unsigned)ix.y << 9) + hd8));
        uint2 s2 = *(const uint2*)(base + (((unsigned)ix.z << 9) + hd8));
        uint2 s3 = *(const uint2*)(base + (((unsigned)ix.w << 9) + hd8));
        a0 += wv.x * bf2f_lo(s0.x); a1 += wv.x * bf2f_hi(s0.x);
        a2 += wv.x * bf2f_lo(s0.y); a3 += wv.x * bf2f_hi(s0.y);
        a0 += wv.y * bf2f_lo(s1.x); a1 += wv.y * bf2f_hi(s1.x);
        a2 += wv.y * bf2f_lo(s1.y); a3 += wv.y * bf2f_hi(s1.y);
        a0 += wv.z * bf2f_lo(s2.x); a1 += wv.z * bf2f_hi(s2.x);
        a2 += wv.z * bf2f_lo(s2.y); a3 += wv.z * bf2f_hi(s2.y);
        a0 += wv.w * bf2f_lo(s3.x); a1 += wv.w * bf2f_hi(s3.x);
        a2 += wv.w * bf2f_lo(s3.y); a3 += wv.w * bf2f_hi(s3.y);
    }
    unsigned o0 = (unsigned)f2bf(a0) | ((unsigned)f2bf(a1) << 16);
    unsigned o1 = (unsigned)f2bf(a2) | ((unsigned)f2bf(a3) << 16);
    uint2 o = {o0, o1};
    *(uint2*)(t_out + (size_t)q * 256 + h * 32 + dg * 4) = o;
}

extern "C" void kernel_launch(void* const* d_in, const int* in_sizes, int n_in,
                              void* d_out, int out_size, void* d_ws, size_t ws_size,
                              hipStream_t stream) {
    const float* query  = (const float*)d_in[0];
    const float* value  = (const float*)d_in[1];
    const float* refpts = (const float*)d_in[2];
    // d_in[3] = spatial_shapes (int32) — fixed {100,50,25,13}^2, hard-coded.
    const float* W_off  = (const float*)d_in[4];
    const float* b_off  = (const float*)d_in[5];
    const float* W_attn = (const float*)d_in[6];
    const float* b_attn = (const float*)d_in[7];
    const float* W_val  = (const float*)d_in[8];
    const float* b_val  = (const float*)d_in[9];
    const float* W_out  = (const float*)d_in[10];
    const float* b_out  = (const float*)d_in[11];

    char* wsp = (char*)d_ws;
    size_t o = 0;
    auto carve = [&](size_t bytes) -> void* {
        void* p = wsp + o; o += (bytes + 255) & ~(size_t)255; return p;
    };
    unsigned short* Wt_val = (unsigned short*)carve(256 * 256 * 2);
    unsigned short* Wt_out = (unsigned short*)carve(256 * 256 * 2);
    unsigned short* Wt_qa  = (unsigned short*)carve(384 * 256 * 2);
    float*          b_qa   = (float*)carve(384 * 4);
    unsigned short* v_buf  = (unsigned short*)carve((size_t)BS * NV * EMBED * 2);
    float*          oa_buf = (float*)carve((size_t)BS * NQ * 384 * 4);
    unsigned short* t_buf  = (unsigned short*)carve((size_t)BS * NQ * EMBED * 2);

    msda_prep_k<<<896, 256, 0, stream>>>(W_val, W_out, W_off, W_attn,
                                         b_off, b_attn, Wt_val, Wt_out, Wt_qa, b_qa);

    // merged: 832 value-GEMM blocks + 750 qa-GEMM blocks, 32 KB dynamic LDS
    msda_gemm_vq_k<<<832 + 750, 256, 32768, stream>>>(value, query, Wt_val, Wt_qa,
                                                      b_val, b_qa, v_buf, oa_buf);
    // sampler reads oa_buf + v_buf, writes t_buf
    msda_sampler_k<<<(BS * NQ) / 4, 256, 0, stream>>>(refpts, oa_buf, v_buf, t_buf);
    // out GEMM reads bf16 t_buf via DMA path: 250 m-tiles x 2 n-tiles
    msda_gemm_out_k<<<500, 256, 24576, stream>>>(t_buf, Wt_out, b_out, (float*)d_out);
}